// Round 6
// baseline (490.258 us; speedup 1.0000x reference)
//
#include <hip/hip_runtime.h>
#include <hip/hip_bf16.h>

// GCN over Block-CSR adjacency. ALL I/O BUFFERS ARE FLOAT32 (reference dtypes).
// Compute: bf16 MFMA, fp32 accumulate; intermediates stored bf16.
//
// Round 12: consolidation to proven-best components, 6 dispatches.
// Evidence: R6/R11 — spmm gather is ceiling-bound at 3.9 TB/s (schedule-invariant);
// bf16-A cut it 93.5->87.1. R9 calibration: ~10us inter-dispatch bubble/kernel.
// R11's L0 reorder lost ~12us -> reverted to champion order. This round:
//  - champion pipeline order: gemm0 -> spmm_ln -> gemm1 -> spmm_ln -> gemm2 -> spmm_out
//  - bf16 A (prep merged INTO the gemm0 dispatch via blockIdx split; both only
//    read inputs -> dependency-safe; prep streams while gemm computes)
//  - W read f32-direct with strided frag build (R11-proven; transpose_all deleted)
//  - spmm_ln / spmm_out byte-identical to R11's measured versions
// Falsifier: if total >=455us, launch bubbles are small and the unexplained
// ~110us is INSIDE gemm/spmm_out -> R13 redesigns those.
//
// ws (128 MiB): zbt0@[64,128) -> h0@[0,64) -> zbt1@[64,128) -> h1@[0,64) ->
// zbt2@[64,80). Ab (bf16 A-values) fills d_out exactly; spmm_out overwrites
// its own wave-private 4KB in place (read->acc->store, race-free, R11-proven).

typedef __bf16 bf16;
typedef bf16 bf16x8 __attribute__((ext_vector_type(8)));
typedef bf16 bf16x4 __attribute__((ext_vector_type(4)));
typedef float f32x4 __attribute__((ext_vector_type(4)));

#define N_NODES 131072
#define BRQ 8192      // block rows (= N/16)
#define KNZ 8         // nonzero blocks per block row
#define IN_F 128
#define HID 256
#define NCLS 64

static __device__ __forceinline__ f32x4 mfma16(bf16x8 a, bf16x8 b, f32x4 c) {
  return __builtin_amdgcn_mfma_f32_16x16x32_bf16(a, b, c, 0, 0, 0);
}

static __device__ __forceinline__ bf16x8 load8(const bf16* p) {
  return *(const bf16x8*)p;
}
static __device__ __forceinline__ bf16x8 cvt8(f32x4 a0, f32x4 a1) {
  bf16x8 r;
  r[0] = (bf16)a0[0]; r[1] = (bf16)a0[1]; r[2] = (bf16)a0[2]; r[3] = (bf16)a0[3];
  r[4] = (bf16)a1[0]; r[5] = (bf16)a1[1]; r[6] = (bf16)a1[2]; r[7] = (bf16)a1[3];
  return r;
}
static __device__ __forceinline__ bf16x8 load8(const float* p) {
  f32x4 a0 = *(const f32x4*)p;
  f32x4 a1 = *(const f32x4*)(p + 4);
  return cvt8(a0, a1);
}

// ---------------- dense GEMM body: B-stationary, W f32-direct --------------------
// Zbt[rt][col][r] = X[N,KIN] @ W[KIN,FOUT]; W read f32 with strided frag build.
template<typename TA, int KIN, int FOUT, int GRID>
static __device__ __forceinline__ void gemm_body(int wgid, int tid,
                                                 const TA* __restrict__ X,
                                                 const float* __restrict__ W,
                                                 bf16* __restrict__ Zbt) {
  constexpr int CG  = FOUT / 64;          // 64-col groups
  constexpr int KS  = KIN / 32;           // K steps
  constexpr int RTS = GRID * 4 / CG;      // row-tile stride (waves per col group)
  constexpr int NT  = BRQ / RTS;          // row-tiles per wave

  const int wave = tid >> 6;
  const int lane = tid & 63;
  const int l15  = lane & 15;
  const int quad = lane >> 4;
  const int gw   = wgid * 4 + wave;
  const int cg   = gw % CG;
  const int rt0  = gw / CG;

  // B-frags from f32 W [KIN][FOUT], strided (L2-resident; once per wave).
  bf16x8 wbf[KS][4];
#pragma unroll
  for (int k = 0; k < KS; ++k)
#pragma unroll
    for (int t = 0; t < 4; ++t) {
      const float* wp = W + (long)(k * 32 + quad * 8) * FOUT + cg * 64 + t * 16 + l15;
      bf16x8 v;
#pragma unroll
      for (int j = 0; j < 8; ++j) v[j] = (bf16)wp[(long)j * FOUT];
      wbf[k][t] = v;
    }

  const TA* __restrict__ xbase = X + (long)l15 * KIN + quad * 8;

  bf16x8 aw[2][KS];
#pragma unroll
  for (int k = 0; k < KS; ++k)
    aw[0][k] = load8(xbase + (long)rt0 * (16 * KIN) + k * 32);

#pragma unroll
  for (int it = 0; it < NT; ++it) {
    const int rt = rt0 + it * RTS;
    if (it + 1 < NT) {
      const long xoff = (long)(rt + RTS) * (16 * KIN);
#pragma unroll
      for (int k = 0; k < KS; ++k)
        aw[(it + 1) & 1][k] = load8(xbase + xoff + k * 32);
    }
    f32x4 acc[4] = {};
#pragma unroll
    for (int k = 0; k < KS; ++k)
#pragma unroll
      for (int t = 0; t < 4; ++t)
        acc[t] = mfma16(aw[it & 1][k], wbf[k][t], acc[t]);
#pragma unroll
    for (int t = 0; t < 4; ++t) {
      int col = cg * 64 + t * 16 + l15;
      bf16x4 v;
#pragma unroll
      for (int i = 0; i < 4; ++i) v[i] = (bf16)acc[t][i];
      *(bf16x4*)(Zbt + ((long)rt * FOUT + col) * 16 + quad * 4) = v;
    }
  }
}

// ---------------- dispatch 1: gemm0 (features @ W0) + A f32->bf16 prep -----------
// blockIdx < 1024: gemm0. blockIdx >= 1024 (8192 WGs): convert bvals to bf16.
// Both branches read only kernel inputs -> dependency-safe in one dispatch.
__global__ __launch_bounds__(256) void gemm0_prep(const float* __restrict__ X,
                                                  const float* __restrict__ W,
                                                  bf16* __restrict__ Zbt,
                                                  const float* __restrict__ V,
                                                  bf16* __restrict__ Ab) {
  if (blockIdx.x < 1024) {
    gemm_body<float, IN_F, HID, 1024>(blockIdx.x, threadIdx.x, X, W, Zbt);
  } else {
    long i = ((long)(blockIdx.x - 1024) * 256 + threadIdx.x) * 8;
    f32x4 a0 = *(const f32x4*)(V + i);
    f32x4 a1 = *(const f32x4*)(V + i + 4);
    *(bf16x8*)(Ab + i) = cvt8(a0, a1);
  }
}

template<int KIN, int FOUT, int GRID>
__global__ __launch_bounds__(256) void gemm_bt2(const bf16* __restrict__ X,
                                                const float* __restrict__ W,
                                                bf16* __restrict__ Zbt) {
  gemm_body<bf16, KIN, FOUT, GRID>(blockIdx.x, threadIdx.x, X, W, Zbt);
}

// ---------------- SpMM + bias + ReLU + LayerNorm (F = HID = 256) — CHAMPION ------
// Byte-identical to R11's measured 87us kernel (bf16 A).
__global__ __launch_bounds__(256) void spmm_ln(const bf16*  __restrict__ Abv,
                                               const int*   __restrict__ Abc,
                                               const bf16*  __restrict__ Zbt,
                                               const float* __restrict__ bias,
                                               const float* __restrict__ gamma,
                                               const float* __restrict__ beta,
                                               bf16* __restrict__ H) {
  const int wave = threadIdx.x >> 6;
  const int lane = threadIdx.x & 63;
  const int l15  = lane & 15;
  const int quad = lane >> 4;
  const int b    = blockIdx.x * 2 + (wave >> 1);
  const int ch   = wave & 1;               // column half

  const int*  bc    = Abc + b * KNZ;
  const int   cst   = (quad & 1) * 8;
  const int   half  = quad >> 1;
  const bf16* abase = Abv + (long)b * (KNZ * 256) + l15 * 16 + cst;

  bf16x8 afr[4];
  long   zb[4];
#pragma unroll
  for (int kp = 0; kp < 4; ++kp) {
    int blk = 2 * kp + half;
    afr[kp] = load8(abase + blk * 256);
    zb[kp]  = (long)bc[blk] * (HID * 16) + cst;
  }
  bf16x8 bfr[4][8];
#pragma unroll
  for (int kp = 0; kp < 4; ++kp)
#pragma unroll
    for (int t = 0; t < 8; ++t) {
      int f = ch * 128 + t * 16 + l15;
      bfr[kp][t] = *(const bf16x8*)(Zbt + zb[kp] + f * 16);
    }

  f32x4 acc[8] = {};
#pragma unroll
  for (int kp = 0; kp < 4; ++kp)
#pragma unroll
    for (int t = 0; t < 8; ++t)
      acc[t] = mfma16(afr[kp], bfr[kp][t], acc[t]);

  // bias + relu in-register, accumulate per-row partial sums
  float gv[8], bv[8];
#pragma unroll
  for (int t = 0; t < 8; ++t) {
    int f = ch * 128 + t * 16 + l15;
    gv[t] = gamma[f];
    bv[t] = beta[f];
  }
  float ps[4] = {0.f, 0.f, 0.f, 0.f}, pss[4] = {0.f, 0.f, 0.f, 0.f};
#pragma unroll
  for (int t = 0; t < 8; ++t) {
    float bi = bias[ch * 128 + t * 16 + l15];
#pragma unroll
    for (int i = 0; i < 4; ++i) {
      float v = acc[t][i] + bi;
      v = v > 0.f ? v : 0.f;
      acc[t][i] = v;
      ps[i] += v;
      pss[i] += v * v;
    }
  }
#pragma unroll
  for (int m = 1; m < 16; m <<= 1) {
#pragma unroll
    for (int i = 0; i < 4; ++i) {
      ps[i]  += __shfl_xor(ps[i], m, 64);
      pss[i] += __shfl_xor(pss[i], m, 64);
    }
  }
  __shared__ float S[4][16], SS[4][16];
  if (l15 == 0) {
#pragma unroll
    for (int i = 0; i < 4; ++i) {
      S[wave][quad * 4 + i]  = ps[i];
      SS[wave][quad * 4 + i] = pss[i];
    }
  }
  __syncthreads();
#pragma unroll
  for (int i = 0; i < 4; ++i) {
    int r = quad * 4 + i;
    float s    = S[wave][r] + S[wave ^ 1][r];
    float ss   = SS[wave][r] + SS[wave ^ 1][r];
    float mu   = s * (1.f / 256.f);
    float var  = ss * (1.f / 256.f) - mu * mu;
    float rstd = rsqrtf(var + 1e-5f);
    bf16* hrow = H + (long)(b * 16 + r) * HID;
#pragma unroll
    for (int t = 0; t < 8; ++t) {
      int f = ch * 128 + t * 16 + l15;
      float y = (acc[t][i] - mu) * rstd * gv[t] + bv[t];
      hrow[f] = (bf16)y;
    }
  }
}

// ---------------- final SpMM + bias (F = NCLS = 64), f32 out — CHAMPION ----------
// A is bf16 and lives in d_out; each wave reads its private 4KB then overwrites
// the exact same 4KB with its f32 output rows (read -> acc -> store, race-free).
__global__ __launch_bounds__(256) void spmm_out(const bf16*  __restrict__ Abv,
                                                const int*   __restrict__ Abc,
                                                const bf16*  __restrict__ Zbt,  // [BRQ,64,16]
                                                const float* __restrict__ bias, // [64]
                                                float* __restrict__ out) {      // [N,64] f32
  const int wave = threadIdx.x >> 6;
  const int b    = blockIdx.x * 4 + wave;   // one block-row per wave
  const int lane = threadIdx.x & 63;
  const int l15  = lane & 15;
  const int quad = lane >> 4;

  const int*  bc    = Abc + b * KNZ;
  const int   cst   = (quad & 1) * 8;
  const int   half  = quad >> 1;
  const bf16* abase = Abv + (long)b * (KNZ * 256) + l15 * 16 + cst;

  bf16x8 afr[4];
  long   zb[4];
#pragma unroll
  for (int kp = 0; kp < 4; ++kp) {
    int blk = 2 * kp + half;
    afr[kp] = load8(abase + blk * 256);
    zb[kp]  = (long)bc[blk] * (NCLS * 16) + cst;
  }
  bf16x8 bfr[4][4];
#pragma unroll
  for (int kp = 0; kp < 4; ++kp)
#pragma unroll
    for (int t = 0; t < 4; ++t) {
      int f = t * 16 + l15;
      bfr[kp][t] = *(const bf16x8*)(Zbt + zb[kp] + f * 16);
    }

  f32x4 acc[4] = {};
#pragma unroll
  for (int kp = 0; kp < 4; ++kp)
#pragma unroll
    for (int t = 0; t < 4; ++t)
      acc[t] = mfma16(afr[kp], bfr[kp][t], acc[t]);

#pragma unroll
  for (int t = 0; t < 4; ++t) {
    int f = t * 16 + l15;
    float bi = bias[f];
#pragma unroll
    for (int i = 0; i < 4; ++i) {
      out[(long)(b * 16 + quad * 4 + i) * NCLS + f] = acc[t][i] + bi;
    }
  }
}

extern "C" void kernel_launch(void* const* d_in, const int* in_sizes, int n_in,
                              void* d_out, int out_size, void* d_ws, size_t ws_size,
                              hipStream_t stream) {
  const float* features = (const float*)d_in[0];
  const float* bvals    = (const float*)d_in[1];
  const float* W0       = (const float*)d_in[2];
  const float* b0v      = (const float*)d_in[3];
  const float* W1       = (const float*)d_in[4];
  const float* b1v      = (const float*)d_in[5];
  const float* W2       = (const float*)d_in[6];
  const float* b2v      = (const float*)d_in[7];
  const float* g0       = (const float*)d_in[8];
  const float* beta0    = (const float*)d_in[9];
  const float* g1       = (const float*)d_in[10];
  const float* beta1    = (const float*)d_in[11];
  const int*   bcols    = (const int*)d_in[12];
  float* outp = (float*)d_out;

  // ws (128 MiB), disjoint lifetimes:
  char* ws = (char*)d_ws;
  bf16* zbt0 = (bf16*)(ws + (64L << 20));    // [64,128)  gemm0   -> spmm_ln0
  bf16* h0   = (bf16*)ws;                    // [0,64)    spmm_ln0-> gemm1
  bf16* zbt1 = (bf16*)(ws + (64L << 20));    // [64,128)  gemm1   -> spmm_ln1 (over dead zbt0)
  bf16* h1   = (bf16*)ws;                    // [0,64)    spmm_ln1-> gemm2 (over dead h0)
  bf16* zbt2 = (bf16*)(ws + (64L << 20));    // [64,80)   gemm2   -> spmm_out (over dead zbt1)

  // bf16 A-values fill d_out exactly (33,554,432 B); spmm_out overwrites in place.
  bf16* Ab = (bf16*)d_out;

  // L0 + prep (one dispatch): zbt0 = features@W0 ; Ab = bf16(bvals)
  gemm0_prep<<<dim3(1024 + BRQ), dim3(256), 0, stream>>>(features, W0, zbt0, bvals, Ab);
  spmm_ln<<<dim3(BRQ / 2), dim3(256), 0, stream>>>(Ab, bcols, zbt0, b0v, g0, beta0, h0);
  // L1
  gemm_bt2<HID, HID, 1024><<<dim3(1024), dim3(256), 0, stream>>>(h0, W1, zbt1);
  spmm_ln<<<dim3(BRQ / 2), dim3(256), 0, stream>>>(Ab, bcols, zbt1, b1v, g1, beta1, h1);
  // OUT
  gemm_bt2<HID, NCLS, 512><<<dim3(512), dim3(256), 0, stream>>>(h1, W2, zbt2);
  spmm_out<<<dim3(BRQ / 4), dim3(256), 0, stream>>>(Ab, bcols, zbt2, b2v, outp);
}

// Round 7
// 445.688 us; speedup vs baseline: 1.1000x; 1.1000x over previous
//
#include <hip/hip_runtime.h>
#include <hip/hip_bf16.h>

// GCN over Block-CSR adjacency. ALL I/O BUFFERS ARE FLOAT32 (reference dtypes).
// Compute: bf16 MFMA, fp32 accumulate; intermediates stored bf16.
//
// Round 13: champion pipeline EXACTLY (f32 A, 93.5us spmm_ln — bf16-A was net
// negative: saves 17us in spmm, costs 18-30us prep, R11/R12 evidence), with ONE
// change: gemm occupancy. Old gemm_bt held W frags in 128 VGPR (total ~220 ->
// ~8 waves/CU, latency-marginal: ~300cy MFMA/iter vs ~900cy HBM). New gemm_lds:
//  - WG's 4 waves share one col-group; W^T [64][KIN+8] bf16 staged into LDS in
//    the prologue DIRECTLY from f32 W (transpose fused -> transpose_all deleted,
//    d_out untouched until spmm_out).
//  - per-iter W frags via ds_read_b128 (padded stride 528B -> balanced banks);
//    an asm-laundered offset per k-step defeats LICM so the compiler can't
//    re-hoist frags into registers (the R7/R10 serialization bug, inverted).
//  - VGPR ~220 -> ~115; __launch_bounds__(256,4) = 16 waves/CU; 1024 WGs = one
//    full residency round. X row-tiles now shared across 4 consecutive WGs
//    (L3-absorbed, 64MB << 256MB) instead of intra-WG.
// spmm_ln / spmm_out: byte-identical to the 462.7us champion.
// Attribution: if total ~410-430, gemm latency was the slack. If ~455-465,
// gemms were fine -> residual is dispatch bubbles -> R14 mega-kernel.
//
// ws (128 MiB): zbt0@[64,128) -> h0@[0,64) -> zbt1@[64,128) -> h1@[0,64) ->
// zbt2@[64,80). d_out written only by spmm_out.

typedef __bf16 bf16;
typedef bf16 bf16x8 __attribute__((ext_vector_type(8)));
typedef bf16 bf16x4 __attribute__((ext_vector_type(4)));
typedef float f32x4 __attribute__((ext_vector_type(4)));

#define N_NODES 131072
#define BRQ 8192      // block rows (= N/16)
#define KNZ 8         // nonzero blocks per block row
#define IN_F 128
#define HID 256
#define NCLS 64

static __device__ __forceinline__ f32x4 mfma16(bf16x8 a, bf16x8 b, f32x4 c) {
  return __builtin_amdgcn_mfma_f32_16x16x32_bf16(a, b, c, 0, 0, 0);
}

static __device__ __forceinline__ bf16x8 load8(const bf16* p) {
  return *(const bf16x8*)p;
}
static __device__ __forceinline__ bf16x8 cvt8(f32x4 a0, f32x4 a1) {
  bf16x8 r;
  r[0] = (bf16)a0[0]; r[1] = (bf16)a0[1]; r[2] = (bf16)a0[2]; r[3] = (bf16)a0[3];
  r[4] = (bf16)a1[0]; r[5] = (bf16)a1[1]; r[6] = (bf16)a1[2]; r[7] = (bf16)a1[3];
  return r;
}
static __device__ __forceinline__ bf16x8 load8(const float* p) {
  f32x4 a0 = *(const f32x4*)p;
  f32x4 a1 = *(const f32x4*)(p + 4);
  return cvt8(a0, a1);
}

// ---------------- dense GEMM: LDS-staged W (high occupancy) ----------------------
// Zbt[rt][col][r] = X[N,KIN] @ W[KIN,FOUT]; W read f32 directly, transposed into
// LDS as bf16 [64][KIN+8] per WG (one col-group per WG, shared by its 4 waves).
template<typename TA, int KIN, int FOUT, int GRID>
__global__ __launch_bounds__(256, 4) void gemm_lds(const TA* __restrict__ X,
                                                   const float* __restrict__ W,
                                                   bf16* __restrict__ Zbt) {
  constexpr int CG  = FOUT / 64;          // 64-col groups
  constexpr int KS  = KIN / 32;           // K steps
  constexpr int WGR = GRID / CG;          // WGs per col group
  constexpr int RTS = WGR * 4;            // row-tile stride
  constexpr int NT  = BRQ / RTS;          // row-tiles per wave
  constexpr int LDW = KIN + 8;            // LDS row stride (+16B pad: 2-way banks)

  const int tid  = threadIdx.x;
  const int wave = tid >> 6;
  const int lane = tid & 63;
  const int l15  = lane & 15;
  const int quad = lane >> 4;
  const int cg   = blockIdx.x % CG;       // consecutive wgids share X row-tiles
  const int rg   = blockIdx.x / CG;
  const int rt0  = rg * 4 + wave;

  __shared__ bf16 WL[64 * LDW];

  // stage W^T col-block: WL[c][k] = W[k][cg*64+c]  (coalesced f32 reads over c)
  for (int e = tid; e < 64 * KIN; e += 256) {
    int c = e & 63, k = e >> 6;
    WL[c * LDW + k] = (bf16)W[(long)k * FOUT + cg * 64 + c];
  }

  const TA* __restrict__ xbase = X + (long)l15 * KIN + quad * 8;

  bf16x8 aw[2][KS];
#pragma unroll
  for (int k = 0; k < KS; ++k)
    aw[0][k] = load8(xbase + (long)rt0 * (16 * KIN) + k * 32);

  __syncthreads();   // prologue only; in-loop LDS is read-only -> no barriers

#pragma unroll
  for (int it = 0; it < NT; ++it) {
    const int rt = rt0 + it * RTS;
    if (it + 1 < NT) {
      const long xoff = (long)(rt + RTS) * (16 * KIN);
#pragma unroll
      for (int k = 0; k < KS; ++k)
        aw[(it + 1) & 1][k] = load8(xbase + xoff + k * 32);
    }
    f32x4 acc[4] = {};
    unsigned lo = 0;
#pragma unroll
    for (int k = 0; k < KS; ++k) {
      asm volatile("" : "+v"(lo));   // opaque offset: blocks LICM re-hoist of W frags
#pragma unroll
      for (int t = 0; t < 4; ++t) {
        bf16x8 wf = *(const bf16x8*)(WL + lo + (t * 16 + l15) * LDW + k * 32 + quad * 8);
        acc[t] = mfma16(aw[it & 1][k], wf, acc[t]);
      }
    }
#pragma unroll
    for (int t = 0; t < 4; ++t) {
      int col = cg * 64 + t * 16 + l15;
      bf16x4 v;
#pragma unroll
      for (int i = 0; i < 4; ++i) v[i] = (bf16)acc[t][i];
      *(bf16x4*)(Zbt + ((long)rt * FOUT + col) * 16 + quad * 4) = v;
    }
  }
}

// ---------------- SpMM + bias + ReLU + LayerNorm (F = HID = 256) — CHAMPION ------
// Byte-identical to the 462.7us champion (f32 A).
__global__ __launch_bounds__(256) void spmm_ln(const float* __restrict__ Abv,
                                               const int*   __restrict__ Abc,
                                               const bf16*  __restrict__ Zbt,
                                               const float* __restrict__ bias,
                                               const float* __restrict__ gamma,
                                               const float* __restrict__ beta,
                                               bf16* __restrict__ H) {
  const int wave = threadIdx.x >> 6;
  const int lane = threadIdx.x & 63;
  const int l15  = lane & 15;
  const int quad = lane >> 4;
  const int b    = blockIdx.x * 2 + (wave >> 1);
  const int ch   = wave & 1;               // column half

  const int*   bc    = Abc + b * KNZ;
  const int    cst   = (quad & 1) * 8;
  const int    half  = quad >> 1;
  const float* abase = Abv + (long)b * (KNZ * 256) + l15 * 16 + cst;

  bf16x8 afr[4];
  long   zb[4];
#pragma unroll
  for (int kp = 0; kp < 4; ++kp) {
    int blk = 2 * kp + half;
    afr[kp] = load8(abase + blk * 256);
    zb[kp]  = (long)bc[blk] * (HID * 16) + cst;
  }
  bf16x8 bfr[4][8];
#pragma unroll
  for (int kp = 0; kp < 4; ++kp)
#pragma unroll
    for (int t = 0; t < 8; ++t) {
      int f = ch * 128 + t * 16 + l15;
      bfr[kp][t] = *(const bf16x8*)(Zbt + zb[kp] + f * 16);
    }

  f32x4 acc[8] = {};
#pragma unroll
  for (int kp = 0; kp < 4; ++kp)
#pragma unroll
    for (int t = 0; t < 8; ++t)
      acc[t] = mfma16(afr[kp], bfr[kp][t], acc[t]);

  // bias + relu in-register, accumulate per-row partial sums
  float gv[8], bv[8];
#pragma unroll
  for (int t = 0; t < 8; ++t) {
    int f = ch * 128 + t * 16 + l15;
    gv[t] = gamma[f];
    bv[t] = beta[f];
  }
  float ps[4] = {0.f, 0.f, 0.f, 0.f}, pss[4] = {0.f, 0.f, 0.f, 0.f};
#pragma unroll
  for (int t = 0; t < 8; ++t) {
    float bi = bias[ch * 128 + t * 16 + l15];
#pragma unroll
    for (int i = 0; i < 4; ++i) {
      float v = acc[t][i] + bi;
      v = v > 0.f ? v : 0.f;
      acc[t][i] = v;
      ps[i] += v;
      pss[i] += v * v;
    }
  }
#pragma unroll
  for (int m = 1; m < 16; m <<= 1) {
#pragma unroll
    for (int i = 0; i < 4; ++i) {
      ps[i]  += __shfl_xor(ps[i], m, 64);
      pss[i] += __shfl_xor(pss[i], m, 64);
    }
  }
  __shared__ float S[4][16], SS[4][16];
  if (l15 == 0) {
#pragma unroll
    for (int i = 0; i < 4; ++i) {
      S[wave][quad * 4 + i]  = ps[i];
      SS[wave][quad * 4 + i] = pss[i];
    }
  }
  __syncthreads();
#pragma unroll
  for (int i = 0; i < 4; ++i) {
    int r = quad * 4 + i;
    float s    = S[wave][r] + S[wave ^ 1][r];
    float ss   = SS[wave][r] + SS[wave ^ 1][r];
    float mu   = s * (1.f / 256.f);
    float var  = ss * (1.f / 256.f) - mu * mu;
    float rstd = rsqrtf(var + 1e-5f);
    bf16* hrow = H + (long)(b * 16 + r) * HID;
#pragma unroll
    for (int t = 0; t < 8; ++t) {
      int f = ch * 128 + t * 16 + l15;
      float y = (acc[t][i] - mu) * rstd * gv[t] + bv[t];
      hrow[f] = (bf16)y;
    }
  }
}

// ---------------- final SpMM + bias (F = NCLS = 64), f32 out — CHAMPION ----------
__global__ __launch_bounds__(256) void spmm_out(const float* __restrict__ Abv,
                                                const int*   __restrict__ Abc,
                                                const bf16*  __restrict__ Zbt,  // [BRQ,64,16]
                                                const float* __restrict__ bias, // [64]
                                                float* __restrict__ out) {      // [N,64] f32
  const int wave = threadIdx.x >> 6;
  const int b    = blockIdx.x * 4 + wave;   // one block-row per wave
  const int lane = threadIdx.x & 63;
  const int l15  = lane & 15;
  const int quad = lane >> 4;

  const int*   bc    = Abc + b * KNZ;
  const int    cst   = (quad & 1) * 8;
  const int    half  = quad >> 1;
  const float* abase = Abv + (long)b * (KNZ * 256) + l15 * 16 + cst;

  bf16x8 afr[4];
  long   zb[4];
#pragma unroll
  for (int kp = 0; kp < 4; ++kp) {
    int blk = 2 * kp + half;
    afr[kp] = load8(abase + blk * 256);
    zb[kp]  = (long)bc[blk] * (NCLS * 16) + cst;
  }
  bf16x8 bfr[4][4];
#pragma unroll
  for (int kp = 0; kp < 4; ++kp)
#pragma unroll
    for (int t = 0; t < 4; ++t) {
      int f = t * 16 + l15;
      bfr[kp][t] = *(const bf16x8*)(Zbt + zb[kp] + f * 16);
    }

  f32x4 acc[4] = {};
#pragma unroll
  for (int kp = 0; kp < 4; ++kp)
#pragma unroll
    for (int t = 0; t < 4; ++t)
      acc[t] = mfma16(afr[kp], bfr[kp][t], acc[t]);

#pragma unroll
  for (int t = 0; t < 4; ++t) {
    int f = t * 16 + l15;
    float bi = bias[f];
#pragma unroll
    for (int i = 0; i < 4; ++i) {
      out[(long)(b * 16 + quad * 4 + i) * NCLS + f] = acc[t][i] + bi;
    }
  }
}

extern "C" void kernel_launch(void* const* d_in, const int* in_sizes, int n_in,
                              void* d_out, int out_size, void* d_ws, size_t ws_size,
                              hipStream_t stream) {
  const float* features = (const float*)d_in[0];
  const float* bvals    = (const float*)d_in[1];
  const float* W0       = (const float*)d_in[2];
  const float* b0v      = (const float*)d_in[3];
  const float* W1       = (const float*)d_in[4];
  const float* b1v      = (const float*)d_in[5];
  const float* W2       = (const float*)d_in[6];
  const float* b2v      = (const float*)d_in[7];
  const float* g0       = (const float*)d_in[8];
  const float* beta0    = (const float*)d_in[9];
  const float* g1       = (const float*)d_in[10];
  const float* beta1    = (const float*)d_in[11];
  const int*   bcols    = (const int*)d_in[12];
  float* outp = (float*)d_out;

  // ws (128 MiB), disjoint lifetimes:
  char* ws = (char*)d_ws;
  bf16* zbt0 = (bf16*)(ws + (64L << 20));    // [64,128)  gemm0    -> spmm_ln0
  bf16* h0   = (bf16*)ws;                    // [0,64)    spmm_ln0 -> gemm1
  bf16* zbt1 = (bf16*)(ws + (64L << 20));    // [64,128)  gemm1    -> spmm_ln1
  bf16* h1   = (bf16*)ws;                    // [0,64)    spmm_ln1 -> gemm2
  bf16* zbt2 = (bf16*)(ws + (64L << 20));    // [64,80)   gemm2    -> spmm_out

  // L0
  gemm_lds<float, IN_F, HID, 1024><<<dim3(1024), dim3(256), 0, stream>>>(features, W0, zbt0);
  spmm_ln<<<dim3(BRQ / 2), dim3(256), 0, stream>>>(bvals, bcols, zbt0, b0v, g0, beta0, h0);
  // L1
  gemm_lds<bf16, HID, HID, 1024><<<dim3(1024), dim3(256), 0, stream>>>(h0, W1, zbt1);
  spmm_ln<<<dim3(BRQ / 2), dim3(256), 0, stream>>>(bvals, bcols, zbt1, b1v, g1, beta1, h1);
  // OUT
  gemm_lds<bf16, HID, NCLS, 512><<<dim3(512), dim3(256), 0, stream>>>(h1, W2, zbt2);
  spmm_out<<<dim3(BRQ / 4), dim3(256), 0, stream>>>(bvals, bcols, zbt2, b2v, outp);
}